// Round 7
// baseline (6663.852 us; speedup 1.0000x reference)
//
#include <hip/hip_runtime.h>

typedef unsigned short u16;
typedef unsigned long long u64;

// ---------------- workspace layout (float units) ----------------
#define OFF_T2    0ull         // GI2 table bf16: [513][16][768] u16
#define OFF_H0    3151872ull   // [16][256] f32 state0
#define OFF_H1    3155968ull   // [3][16][256] h1 slots (owner-written, 3-slot rotation)
#define OFF_QACC  3168256ull   // [3][16][256] query accumulator (atomicAdd)
#define OFF_GH2A  3180544ull   // [3][16][768] gh2 accumulator (atomicAdd)
#define OFF_CLSA  3217408ull   // [3][16][16]  cls-logit accumulator
#define OFF_SMX   3218176ull   // u64[2][16][16][16]: {epoch|payload} smx records
#define OFF_FLG   3234560ull   // [16 g][16 j][16 u32] epoch flags, 64B/flag
#define WS_END    3238656ull   // 12.95 MB

__device__ __forceinline__ float b2f(u16 u){
  union { unsigned int i; float f; } x; x.i = ((unsigned int)u) << 16; return x.f;
}
__device__ __forceinline__ u16 f2b(float f){
  union { float f; unsigned int i; } x; x.f = f;
  unsigned int lsb = (x.i >> 16) & 1u;
  unsigned int r = x.i + 0x7fffu + lsb;
  return (u16)(r >> 16);
}
__device__ __forceinline__ float tanh_fast(float x){
  float e = __expf(2.f*x);
  return 1.f - 2.f/(e + 1.f);
}
__device__ __forceinline__ float sigm_fast(float x){
  return 1.f/(1.f + __expf(-x));
}
// agent-scope relaxed atomics
__device__ __forceinline__ float ldc(const float* p){
  return __hip_atomic_load((float*)p, __ATOMIC_RELAXED, __HIP_MEMORY_SCOPE_AGENT);
}
__device__ __forceinline__ void stc(float* p, float v){
  __hip_atomic_store(p, v, __ATOMIC_RELAXED, __HIP_MEMORY_SCOPE_AGENT);
}
__device__ __forceinline__ void adc(float* p, float v){
  __hip_atomic_fetch_add(p, v, __ATOMIC_RELAXED, __HIP_MEMORY_SCOPE_AGENT);
}
__device__ __forceinline__ u64 ld64(const u64* p){
  return __hip_atomic_load((u64*)p, __ATOMIC_RELAXED, __HIP_MEMORY_SCOPE_AGENT);
}
__device__ __forceinline__ void st64(u64* p, u64 v){
  __hip_atomic_store(p, v, __ATOMIC_RELAXED, __HIP_MEMORY_SCOPE_AGENT);
}
__device__ __forceinline__ unsigned fu(float f){
  union { float f; unsigned int i; } x; x.f = f; return x.i;
}
__device__ __forceinline__ float uf(unsigned u){
  union { unsigned int i; float f; } x; x.i = u; return x.f;
}

// ---------------- init: zero accumulators + smx tags + flags ----------------
__global__ void init_k(float* __restrict__ ws){
  unsigned* p = (unsigned*)(ws + OFF_QACC);
  const int n = (int)(WS_END - OFF_QACC);
  for (int i = blockIdx.x*256 + threadIdx.x; i < n; i += gridDim.x*256)
    p[i] = 0u;
}

// ---------------- state0 ----------------
__global__ void state0_k(const float* __restrict__ feats, const float* __restrict__ w_si,
                         const float* __restrict__ b_si, float* __restrict__ ws){
  const int b = blockIdx.x, tid = threadIdx.x;
  __shared__ float S[256];
  const float* row = feats + ((size_t)(b*256 + tid))*512;
  float a0=0.f,a1=0.f,a2=0.f,a3=0.f;
  for (int n=0;n<512;n+=4){ a0+=row[n]; a1+=row[n+1]; a2+=row[n+2]; a3+=row[n+3]; }
  S[tid] = (a0+a1)+(a2+a3);
  __syncthreads();
  const float* wr = w_si + (size_t)tid*256;
  float acc = 0.f;
  for (int c=0;c<256;c++) acc += wr[c]*S[c];
  ws[OFF_H0 + b*256 + tid] = acc/513.f + b_si[tid];
}

// ---------------- GI2 table ----------------
__global__ __launch_bounds__(256,2) void precomp_k(
    const float* __restrict__ feats,
    const float* __restrict__ w_ih2, const float* __restrict__ b_ih2,
    float* __restrict__ ws)
{
  const int xc = blockIdx.x;
  const int b  = blockIdx.y;
  const int tid = threadIdx.x;
  __shared__ __align__(16) float fc[256][36];
  {
    const float* fr = feats + ((size_t)(b*256 + tid))*512;
    for (int xx=0; xx<32; ++xx){
      int col = xc*32 + xx;
      fc[tid][xx] = (col >= 1 && col <= 512) ? fr[col-1] : 0.f;
    }
  }
  __syncthreads();
  const float* r0 = w_ih2 + (size_t)tid*256;
  const float* r1 = w_ih2 + (size_t)(tid+256)*256;
  const float* r2 = w_ih2 + (size_t)(tid+512)*256;
  float bb0 = b_ih2[tid], bb1 = b_ih2[tid+256], bb2 = b_ih2[tid+512];
  float acc0[32], acc1[32], acc2[32];
  #pragma unroll
  for (int xx=0; xx<32; ++xx){ acc0[xx]=bb0; acc1[xx]=bb1; acc2[xx]=bb2; }
  for (int c=0; c<256; ++c){
    float w0 = r0[c], w1 = r1[c], w2 = r2[c];
    const float* cb = &fc[c][0];
    #pragma unroll
    for (int xx=0; xx<32; ++xx){ acc0[xx]+=w0*cb[xx]; acc1[xx]+=w1*cb[xx]; acc2[xx]+=w2*cb[xx]; }
  }
  u16* tbl = (u16*)(ws + OFF_T2);
  for (int xx=0; xx<32; ++xx){
    int col = xc*32 + xx;
    if (col > 512) continue;
    size_t base = ((size_t)col*16 + b)*768;
    tbl[base + tid]       = f2b(acc0[xx]);
    tbl[base + 256 + tid] = f2b(acc1[xx]);
    tbl[base + 512 + tid] = f2b(acc2[xx]);
  }
}

// ---------------- split barrier (BAR A only) ----------------
__device__ __forceinline__ void bar_arrive(unsigned* flg, int j, unsigned ep){
  __builtin_amdgcn_s_waitcnt(0);
  __syncthreads();
  if (threadIdx.x == 0)
    __hip_atomic_store(flg + j*16, ep, __ATOMIC_RELAXED, __HIP_MEMORY_SCOPE_AGENT);
}
__device__ __forceinline__ void bar_wait(unsigned* flg, unsigned ep){
  if (threadIdx.x < 16){
    while (__hip_atomic_load(flg + threadIdx.x*16, __ATOMIC_RELAXED, __HIP_MEMORY_SCOPE_AGENT) < ep)
      __builtin_amdgcn_s_sleep(1);
  }
  __syncthreads();
}

// ---------------- persistent scan kernel ----------------
__global__ __launch_bounds__(256, 1) void persist_k(
    const float* __restrict__ feats,
    const float* __restrict__ w_fp,  const float* __restrict__ b_fp,
    const float* __restrict__ w_ih1, const float* __restrict__ b_ih1,
    const float* __restrict__ w_hh1, const float* __restrict__ b_hh1,
    const float* __restrict__ w_hh2, const float* __restrict__ b_hh2,
    const float* __restrict__ w_q,   const float* __restrict__ b_q,
    const float* __restrict__ w_cov, const float* __restrict__ b_cov,
    const float* __restrict__ w_cum, const float* __restrict__ b_cum,
    const float* __restrict__ w_logit, const float* __restrict__ b_logit,
    const float* __restrict__ w_c1,  const float* __restrict__ b_c1,
    const float* __restrict__ w_c2,  const float* __restrict__ b_c2,
    float* __restrict__ ws, float* __restrict__ d_out)
{
  const int tid  = threadIdx.x;
  const int g    = blockIdx.x & 15;
  const int j    = blockIdx.x >> 4;
  const int lane = tid & 63;
  const int wv   = tid >> 6;

  float* out_pred = d_out;              // [512][16]
  float* out_att  = d_out + 8192;       // [512][16][512]
  const u16* tbl2 = (const u16*)(ws + OFF_T2);

  __shared__ __align__(16) float proj_l[32*256];
  __shared__ __align__(16) float fpl[32*256];     // staged conv+proj partials
  __shared__ __align__(16) float fstage[256][9];
  __shared__ float h2s[256];
  __shared__ __align__(16) float query_s[256];
  __shared__ float cbuf[2][256];
  __shared__ float cbuf2[256];
  __shared__ float ctxP[256];
  __shared__ float saw_s[40], csaw_s[40];
  __shared__ float gh1_l[48], gi1_s[48], h1n_l[16], tanh_l[16];
  __shared__ float smx_l[256];
  __shared__ float wsm[4], wss[4], wvv[4], wii[4], hi_l[3];
  __shared__ float att_l[32];
  __shared__ float payl[16];
  __shared__ float wc2s[4][16];

  // ---- register weights ----
  float wcov[4][7], wcum[4][7], wl[4];
  #pragma unroll
  for (int u=0; u<4; ++u){
    int p = 4*lane + u;
    wl[u] = w_logit[p];
    #pragma unroll
    for (int k=0; k<7; ++k){ wcov[u][k] = w_cov[p*7+k]; wcum[u][k] = w_cum[p*7+k]; }
  }
  const float blog = b_logit[0];
  const float bc20 = b_c2[0], bc21 = b_c2[1], bc22 = b_c2[2], bc23 = b_c2[3];

  const int ol = tid >> 2;
  const int qq = tid & 3;
  float bh1=0.f, bi1=0.f;
  float wh1[64], wih1[64];
  if (ol < 48){
    int gate = ol >> 4, u = ol & 15;
    int grow = gate*256 + 16*j + u;
    bh1 = b_hh1[grow]; bi1 = b_ih1[grow];
    #pragma unroll
    for (int i=0; i<64; ++i){
      wh1[i]  = w_hh1[(size_t)grow*256 + qq + 4*i];
      wih1[i] = w_ih1[(size_t)grow*256 + qq + 4*i];
    }
  } else {
    #pragma unroll
    for (int i=0; i<64; ++i){ wh1[i]=0.f; wih1[i]=0.f; }
  }
  float wqr[16];
  #pragma unroll
  for (int i=0; i<16; ++i) wqr[i] = w_q[(size_t)tid*512 + 256 + 16*j + i];
  float w2c[3][16], bg2[3];
  #pragma unroll
  for (int k=0; k<3; ++k){
    bg2[k] = b_hh2[tid + 256*k];
    #pragma unroll
    for (int i=0; i<16; ++i) w2c[k][i] = w_hh2[(size_t)(tid + 256*k)*256 + 16*j + i];
  }

  const int c_ol = tid >> 4, c_qp = tid & 15;
  const int prow = 16*j + c_ol;
  float wc1r[16], wcc[16], wcp[16], wqc[16];
  #pragma unroll
  for (int i=0; i<16; ++i){
    wc1r[i] = w_c1[(size_t)prow*768 + 512 + c_qp + 16*i];
    wcc[i]  = w_c1[(size_t)prow*768 +   0 + c_qp + 16*i];
    wcp[i]  = w_c1[(size_t)prow*768 + 256 + c_qp + 16*i];
    wqc[i]  = w_q [(size_t)prow*512 +   0 + c_qp + 16*i];
  }
  const float bcl = b_c1[prow];
  const float bqc = b_q[prow] + b_cov[prow] + b_cum[prow];

  if (tid < 64) wc2s[tid>>4][tid&15] = w_c2[(tid>>4)*256 + 16*j + (tid&15)];
  if (tid < 40){ saw_s[tid] = 0.f; csaw_s[tid] = 0.f; }

  // ---- prologue ----
  cbuf[0][tid] = feats[(size_t)(g*256 + tid)*512 + 0];
  cbuf[1][tid] = feats[(size_t)(g*256 + tid)*512 + 1];
  h2s[tid] = ws[OFF_H0 + g*256 + tid];
  {
    const float* fr = feats + ((size_t)(g*256 + tid))*512;
    const float* wr = w_fp + (size_t)tid*256;
    const float bfp = b_fp[tid];
    for (int z=0; z<4; ++z){
      for (int cc=0; cc<8; ++cc){
        int pos = 32*j + 8*z + cc;
        fstage[tid][cc] = (pos >= 1) ? fr[pos-1] : 0.f;
      }
      __syncthreads();
      float pacc[8] = {0,0,0,0,0,0,0,0};
      for (int c=0; c<256; ++c){
        float w = wr[c];
        #pragma unroll
        for (int cc=0; cc<8; ++cc) pacc[cc] += w * fstage[c][cc];
      }
      __syncthreads();
      #pragma unroll
      for (int cc=0; cc<8; ++cc) proj_l[(8*z+cc)*256 + tid] = pacc[cc] + bfp;
    }
  }
  __syncthreads();
  if (ol < 48){                // gh1(0), gi1(0)
    float s1 = 0.f, s2 = 0.f;
    #pragma unroll
    for (int i=0; i<64; ++i){
      s1 += wh1[i]*h2s[qq + 4*i];
      s2 += wih1[i]*cbuf[0][qq + 4*i];
    }
    s1 += __shfl_xor(s1, 1, 64); s1 += __shfl_xor(s1, 2, 64);
    s2 += __shfl_xor(s2, 1, 64); s2 += __shfl_xor(s2, 2, 64);
    if (qq == 0){ gh1_l[ol] = s1 + bh1; gi1_s[ol] = s2 + bi1; }
  }
  __syncthreads();
  if (tid < 16){               // h1(0) -> H1 slot 0
    int ig = 16*j + tid;
    float r  = sigm_fast(gi1_s[tid]      + gh1_l[tid]);
    float z  = sigm_fast(gi1_s[16 + tid] + gh1_l[16 + tid]);
    float nn = tanh_fast(gi1_s[32 + tid] + r*gh1_l[32 + tid]);
    float h1v = (1.f - z)*nn + z*h2s[ig];
    stc(ws + OFF_H1 + (size_t)(0*16 + g)*256 + ig, h1v);
    h1n_l[tid] = h1v;
  }
  __syncthreads();
  {                            // qh(0) -> QACC slot0
    float qs = 0.f;
    #pragma unroll
    for (int i=0; i<16; ++i) qs += wqr[i]*h1n_l[i];
    adc(ws + OFF_QACC + (size_t)(0*16 + g)*256 + tid, qs);
  }
  #pragma unroll
  for (int k=0; k<3; ++k){     // gh2(0) fold -> GH2A slot0 (+bias), bias -> slot1
    float gs = 0.f;
    #pragma unroll
    for (int i=0; i<16; ++i) gs += w2c[k][i]*h1n_l[i];
    if (j == 15) gs += bg2[k];
    adc(ws + OFF_GH2A + (size_t)(0*16 + g)*768 + 256*k + tid, gs);
    if (j == 15) adc(ws + OFF_GH2A + (size_t)(1*16 + g)*768 + 256*k + tid, bg2[k]);
  }
  {                            // qc(0)->slot0, qc(1)->slot1
    float s0v = 0.f, s1v = 0.f;
    #pragma unroll
    for (int i=0; i<16; ++i){ s0v += wqc[i]*cbuf[0][c_qp + 16*i]; s1v += wqc[i]*cbuf[1][c_qp + 16*i]; }
    s0v += __shfl_xor(s0v, 1, 64); s0v += __shfl_xor(s0v, 2, 64);
    s0v += __shfl_xor(s0v, 4, 64); s0v += __shfl_xor(s0v, 8, 64);
    s1v += __shfl_xor(s1v, 1, 64); s1v += __shfl_xor(s1v, 2, 64);
    s1v += __shfl_xor(s1v, 4, 64); s1v += __shfl_xor(s1v, 8, 64);
    if (c_qp == 0){
      adc(ws + OFF_QACC + (size_t)(0*16 + g)*256 + prow, s0v + bqc);
      adc(ws + OFF_QACC + (size_t)(1*16 + g)*256 + prow, s1v + bqc);
    }
  }
  if (j == 0 && tid < 4){      // CLSA bias seed, slots 0..2
    stc(ws + OFF_CLSA + (size_t)(0*16 + g)*16 + tid, b_c2[tid]);
    stc(ws + OFF_CLSA + (size_t)(1*16 + g)*16 + tid, b_c2[tid]);
    stc(ws + OFF_CLSA + (size_t)(2*16 + g)*16 + tid, b_c2[tid]);
  }

  unsigned* flg = (unsigned*)(ws + OFF_FLG) + g*256;
  unsigned ep = 0;
  bar_arrive(flg, j, ++ep);

  // partials for t=0 into fpl (saw/csaw are zero), overlapping peers' arrival
  #pragma unroll
  for (int i=0; i<8; ++i){
    int ln = 8*wv + i;
    float4 pj = *(const float4*)&proj_l[ln*256 + 4*lane];
    float pv[4] = {pj.x, pj.y, pj.z, pj.w};
    float sw[7], cw[7];
    #pragma unroll
    for (int k=0; k<7; ++k){ sw[k] = saw_s[ln+k]; cw[k] = csaw_s[ln+k]; }
    float f4o[4];
    #pragma unroll
    for (int u=0; u<4; ++u){
      float f = pv[u];
      #pragma unroll
      for (int k=0; k<7; ++k) f += wcov[u][k]*sw[k] + wcum[u][k]*cw[k];
      f4o[u] = f;
    }
    *(float4*)&fpl[ln*256 + 4*lane] = make_float4(f4o[0], f4o[1], f4o[2], f4o[3]);
  }

  for (int t = 0; t < 512; ++t){
    const int s0 = t % 3, s1 = (t+1) % 3, s2 = (t+2) % 3;
    const unsigned need = (unsigned)(t + 1);
    u64* SMXs = (u64*)(ws + OFF_SMX) + ((size_t)((t&1)*16 + g)*256);  // [16 rec][16 u64]
    bar_wait(flg, ep);           // detection overlapped by shadow+partials of t-1
    // ================= P1 =================
    float qw = ldc(ws + OFF_QACC + (size_t)(s0*16 + g)*256 + tid);
    if (t < 511) cbuf[(t+1)&1][tid] = feats[(size_t)(g*256 + tid)*512 + (t+1)];
    query_s[tid] = qw;
    __syncthreads();
    float lgv[8];
    {
      float qv[4];
      { float4 q4 = *(const float4*)&query_s[4*lane]; qv[0]=q4.x; qv[1]=q4.y; qv[2]=q4.z; qv[3]=q4.w; }
      #pragma unroll
      for (int i=0; i<8; ++i){
        int ln = 8*wv + i;
        float4 f4 = *(const float4*)&fpl[ln*256 + 4*lane];
        float fpv[4] = {f4.x, f4.y, f4.z, f4.w};
        float sa = 0.f;
        #pragma unroll
        for (int u=0; u<4; ++u) sa += wl[u]*tanh_fast(fpv[u] + qv[u]);
        #pragma unroll
        for (int mm=32; mm>=1; mm>>=1) sa += __shfl_xor(sa, mm, 64);
        lgv[i] = sa + blog;
      }
    }
    // ---- per-wave smx reduce ----
    if (lane == 0){
      float wm = -3.0e38f;
      #pragma unroll
      for (int i=0; i<8; ++i){ int n = 32*j + 8*wv + i; if (n <= t) wm = fmaxf(wm, lgv[i]); }
      wsm[wv] = wm;
      if (wv == 3){ hi_l[0] = lgv[5]; hi_l[1] = lgv[6]; hi_l[2] = lgv[7]; }
    }
    __syncthreads();
    if (lane == 0){
      float bm = fmaxf(fmaxf(wsm[0], wsm[1]), fmaxf(wsm[2], wsm[3]));
      float sm = 0.f, bv = -3.0e38f; int bi = 32*j;
      #pragma unroll
      for (int i=0; i<8; ++i){
        int n = 32*j + 8*wv + i;
        if (n <= t){ sm += __expf(lgv[i] - bm); if (lgv[i] > bv){ bv = lgv[i]; bi = n; } }
      }
      wss[wv] = sm; wvv[wv] = bv; wii[wv] = (float)bi;
    }
    __syncthreads();
    if (tid == 0){               // build record payload (10 words)
      float bm = fmaxf(fmaxf(wsm[0], wsm[1]), fmaxf(wsm[2], wsm[3]));
      float sm = wss[0] + wss[1] + wss[2] + wss[3];
      float bv = wvv[0]; float bi = wii[0];
      if (wvv[1] > bv){ bv = wvv[1]; bi = wii[1]; }
      if (wvv[2] > bv){ bv = wvv[2]; bi = wii[2]; }
      if (wvv[3] > bv){ bv = wvv[3]; bi = wii[3]; }
      payl[0] = bm; payl[1] = sm; payl[2] = bv; payl[3] = bi;
      payl[4] = lgv[0]; payl[5] = lgv[1]; payl[6] = lgv[2];
      payl[7] = hi_l[0]; payl[8] = hi_l[1]; payl[9] = hi_l[2];
    }
    // same wave (lanes 0..9 of wave0): program-order after tid0's LDS writes
    if (tid < 10)
      st64(SMXs + j*16 + tid, ((u64)need << 32) | (u64)fu(payl[tid]));
    // ---- post-record shadow ----
    float h1r = ldc(ws + OFF_H1 + (size_t)(s0*16 + g)*256 + tid);
    float ga0, ga1, ga2;
    {
      const float* gb = ws + OFF_GH2A + (size_t)(s0*16 + g)*768;
      ga0 = ldc(gb + tid); ga1 = ldc(gb + 256 + tid); ga2 = ldc(gb + 512 + tid);
    }
    if (lane == 0){
      #pragma unroll
      for (int i=0; i<8; ++i) att_l[8*wv + i] = lgv[i];
    }
    if (t < 511 && ol < 48){     // gi1(t+1): input part
      const float* cN = cbuf[(t+1)&1];
      float sgi = 0.f;
      #pragma unroll
      for (int i=0; i<64; ++i) sgi += wih1[i]*cN[qq + 4*i];
      sgi += __shfl_xor(sgi, 1, 64); sgi += __shfl_xor(sgi, 2, 64);
      if (qq == 0) gi1_s[ol] = sgi + bi1;
    }
    __syncthreads();
    if (tid < 32)
      out_att[((size_t)t*16 + g)*512 + 32*j + tid] = att_l[tid];
    if (t >= 2 && j == 0 && tid == 0){   // pred(t-2) finalize + slot reset
      float* cb = ws + OFF_CLSA + (size_t)(((t-2)%3)*16 + g)*16;
      float v0 = ldc(cb+0), v1 = ldc(cb+1), v2 = ldc(cb+2), v3 = ldc(cb+3);
      int pb = 0; float bv = v0;
      if (v1 > bv){ bv = v1; pb = 1; }
      if (v2 > bv){ bv = v2; pb = 2; }
      if (v3 > bv){ bv = v3; pb = 3; }
      out_pred[(t-2)*16 + g] = (float)pb;
      stc(cb+0, bc20); stc(cb+1, bc21); stc(cb+2, bc22); stc(cb+3, bc23);
    }
    // ================= P2 =================
    {
      const int r = tid >> 4, w = tid & 15;
      if (w < 10){
        const u64* p = SMXs + r*16 + w;
        u64 v = ld64(p);
        while ((unsigned)(v >> 32) < need){
          __builtin_amdgcn_s_sleep(1);
          v = ld64(p);
        }
        smx_l[r*16 + w] = uf((unsigned)v);
      }
    }
    if (t < 510) cbuf2[tid] = feats[(size_t)(g*256 + tid)*512 + (t+2)];
    __syncthreads();
    // combine: M, Z, argmax
    float M, invZ; int idx;
    {
      M = -3.0e38f;
      #pragma unroll
      for (int jj=0; jj<16; ++jj) M = fmaxf(M, smx_l[16*jj]);
      float Z = 0.f, bv = -3.0e38f, bif = 0.f;
      #pragma unroll
      for (int jj=0; jj<16; ++jj){
        Z += smx_l[16*jj+1]*__expf(smx_l[16*jj] - M);
        float v = smx_l[16*jj+2];
        if (v > bv){ bv = v; bif = smx_l[16*jj+3]; }
      }
      invZ = 1.f/Z; idx = (int)bif;
    }
    // issue tbl2 loads early
    const u16* t2 = tbl2 + ((size_t)idx*16 + g)*768;
    float gr = b2f(t2[tid]), gz = b2f(t2[256 + tid]), gn = b2f(t2[512 + tid]);
    // saw/csaw update (disjoint writers)
    if (lane == 0){
      #pragma unroll
      for (int i=0; i<8; ++i){
        int n = 32*j + 8*wv + i;
        float a = (n <= t) ? __expf(lgv[i] - M)*invZ : 0.f;
        saw_s[3 + 8*wv + i] = a; csaw_s[3 + 8*wv + i] += a;
      }
    } else if (tid >= 8 && tid < 11){
      int w = tid - 8; int r = 32*j - 3 + w;
      float a = 0.f;
      if (j > 0 && r <= t) a = __expf(smx_l[16*(j-1) + 7 + w] - M)*invZ;
      saw_s[w] = a; csaw_s[w] += a;
    } else if (tid >= 11 && tid < 14){
      int k = tid - 11; int r = 32*j + 32 + k;
      float a = 0.f;
      if (j < 15 && r <= t) a = __expf(smx_l[16*(j+1) + 4 + k] - M)*invZ;
      saw_s[35 + k] = a; csaw_s[35 + k] += a;
    }
    // h2(t)
    float h2v;
    {
      float r  = sigm_fast(gr + ga0);
      float z  = sigm_fast(gz + ga1);
      float nn = tanh_fast(gn + r*ga2);
      h2v = (1.f - z)*nn + z*h1r;
    }
    __syncthreads();
    h2s[tid] = h2v;
    __syncthreads();
    if (t < 511 && ol < 48){     // gh1(t+1): hidden part
      float sg = 0.f;
      #pragma unroll
      for (int i=0; i<64; ++i) sg += wh1[i]*h2s[qq + 4*i];
      sg += __shfl_xor(sg, 1, 64); sg += __shfl_xor(sg, 2, 64);
      if (qq == 0) gh1_l[ol] = sg + bh1;
    }
    __syncthreads();
    if (t < 511 && tid < 16){    // h1(t+1) own rows -> H1 slot s1
      int ig = 16*j + tid;
      float r  = sigm_fast(gi1_s[tid]      + gh1_l[tid]);
      float z  = sigm_fast(gi1_s[16 + tid] + gh1_l[16 + tid]);
      float nn = tanh_fast(gi1_s[32 + tid] + r*gh1_l[32 + tid]);
      float h1v = (1.f - z)*nn + z*h2s[ig];
      stc(ws + OFF_H1 + (size_t)(s1*16 + g)*256 + ig, h1v);
      h1n_l[tid] = h1v;
    }
    __syncthreads();
    if (t < 511){                // folds into slot s1
      float qs = 0.f;
      #pragma unroll
      for (int i=0; i<16; ++i) qs += wqr[i]*h1n_l[i];
      adc(ws + OFF_QACC + (size_t)(s1*16 + g)*256 + tid, qs);
      #pragma unroll
      for (int k=0; k<3; ++k){
        float gs = 0.f;
        #pragma unroll
        for (int i=0; i<16; ++i) gs += w2c[k][i]*h1n_l[i];
        adc(ws + OFF_GH2A + (size_t)(s1*16 + g)*768 + 256*k + tid, gs);
      }
    }
    if (t < 510){                // resets of slot s2
      float qn = 0.f;
      #pragma unroll
      for (int i=0; i<16; ++i) qn += wqc[i]*cbuf2[c_qp + 16*i];
      qn += __shfl_xor(qn, 1, 64); qn += __shfl_xor(qn, 2, 64);
      qn += __shfl_xor(qn, 4, 64); qn += __shfl_xor(qn, 8, 64);
      if (c_qp == 0) stc(ws + OFF_QACC + (size_t)(s2*16 + g)*256 + prow, qn + bqc);
      if (j == 15){
        float* gb = ws + OFF_GH2A + (size_t)(s2*16 + g)*768;
        stc(gb + tid, bg2[0]); stc(gb + 256 + tid, bg2[1]); stc(gb + 512 + tid, bg2[2]);
      }
    }
    bar_arrive(flg, j, ++ep);    // arrive; detection overlapped by work below
    // -------- shadow: off-recurrence work --------
    ctxP[tid] = (idx >= 1) ? feats[(size_t)(g*256 + tid)*512 + idx - 1] : 0.f;
    __syncthreads();
    {
      const float* cT = cbuf[t&1];
      float sc = 0.f;
      #pragma unroll
      for (int i=0; i<16; ++i){
        int d = c_qp + 16*i;
        sc += wc1r[i]*h2s[d] + wcc[i]*cT[d] + wcp[i]*ctxP[d];
      }
      sc += __shfl_xor(sc, 1, 64); sc += __shfl_xor(sc, 2, 64);
      sc += __shfl_xor(sc, 4, 64); sc += __shfl_xor(sc, 8, 64);
      if (c_qp == 0) tanh_l[c_ol] = tanh_fast(sc + bcl);
    }
    __syncthreads();
    if (tid < 4){                // CLSA adds into slot s0
      float sum = 0.f;
      #pragma unroll
      for (int o=0; o<16; ++o) sum += wc2s[tid][o]*tanh_l[o];
      adc(ws + OFF_CLSA + (size_t)(s0*16 + g)*16 + tid, sum);
    }
    if (t < 511){                // conv+proj partials for t+1 -> fpl (barrier shadow)
      #pragma unroll
      for (int i=0; i<8; ++i){
        int ln = 8*wv + i;
        float4 pj = *(const float4*)&proj_l[ln*256 + 4*lane];
        float pv[4] = {pj.x, pj.y, pj.z, pj.w};
        float sw[7], cw[7];
        #pragma unroll
        for (int k=0; k<7; ++k){ sw[k] = saw_s[ln+k]; cw[k] = csaw_s[ln+k]; }
        float f4o[4];
        #pragma unroll
        for (int u=0; u<4; ++u){
          float f = pv[u];
          #pragma unroll
          for (int k=0; k<7; ++k) f += wcov[u][k]*sw[k] + wcum[u][k]*cw[k];
          f4o[u] = f;
        }
        *(float4*)&fpl[ln*256 + 4*lane] = make_float4(f4o[0], f4o[1], f4o[2], f4o[3]);
      }
    }
  }
  // tail: pred(510), pred(511)
  bar_arrive(flg, j, ++ep); bar_wait(flg, ep);
  if (j == 0 && tid == 0){
    #pragma unroll
    for (int tt=510; tt<512; ++tt){
      float* cb = ws + OFF_CLSA + (size_t)((tt%3)*16 + g)*16;
      float v0 = ldc(cb+0), v1 = ldc(cb+1), v2 = ldc(cb+2), v3 = ldc(cb+3);
      int pb = 0; float bv = v0;
      if (v1 > bv){ bv = v1; pb = 1; }
      if (v2 > bv){ bv = v2; pb = 2; }
      if (v3 > bv){ bv = v3; pb = 3; }
      out_pred[tt*16 + g] = (float)pb;
    }
  }
}

extern "C" void kernel_launch(void* const* d_in, const int* in_sizes, int n_in,
                              void* d_out, int out_size, void* d_ws, size_t ws_size,
                              hipStream_t stream)
{
  (void)in_sizes; (void)n_in; (void)out_size; (void)ws_size;
  const float* feats   = (const float*)d_in[0];
  const float* w_fp    = (const float*)d_in[2];
  const float* b_fp    = (const float*)d_in[3];
  const float* w_si    = (const float*)d_in[4];
  const float* b_si    = (const float*)d_in[5];
  const float* w_ih1   = (const float*)d_in[6];
  const float* w_hh1   = (const float*)d_in[7];
  const float* b_ih1   = (const float*)d_in[8];
  const float* b_hh1   = (const float*)d_in[9];
  const float* w_ih2   = (const float*)d_in[10];
  const float* w_hh2   = (const float*)d_in[11];
  const float* b_ih2   = (const float*)d_in[12];
  const float* b_hh2   = (const float*)d_in[13];
  const float* w_q     = (const float*)d_in[14];
  const float* b_q     = (const float*)d_in[15];
  const float* w_cov   = (const float*)d_in[16];
  const float* b_cov   = (const float*)d_in[17];
  const float* w_cum   = (const float*)d_in[18];
  const float* b_cum   = (const float*)d_in[19];
  const float* w_logit = (const float*)d_in[20];
  const float* b_logit = (const float*)d_in[21];
  const float* w_c1    = (const float*)d_in[22];
  const float* b_c1    = (const float*)d_in[23];
  const float* w_c2    = (const float*)d_in[24];
  const float* b_c2    = (const float*)d_in[25];
  float* ws  = (float*)d_ws;
  float* out = (float*)d_out;

  init_k<<<64, 256, 0, stream>>>(ws);
  state0_k<<<16, 256, 0, stream>>>(feats, w_si, b_si, ws);
  precomp_k<<<dim3(17,16), 256, 0, stream>>>(feats, w_ih2, b_ih2, ws);
  persist_k<<<256, 256, 0, stream>>>(feats, w_fp, b_fp, w_ih1, b_ih1,
                                     w_hh1, b_hh1, w_hh2, b_hh2,
                                     w_q, b_q, w_cov, b_cov, w_cum, b_cum,
                                     w_logit, b_logit, w_c1, b_c1, w_c2, b_c2,
                                     ws, out);
}

// Round 8
// 6197.829 us; speedup vs baseline: 1.0752x; 1.0752x over previous
//
#include <hip/hip_runtime.h>

typedef unsigned short u16;
typedef unsigned long long u64;

// ---------------- workspace layout (float units) ----------------
#define OFF_T2    0ull         // GI2 table bf16: [513][16][768] u16
#define OFF_H0    3151872ull   // [16][256] f32 state0
#define OFF_H1    3155968ull   // [3][16][256] h1 slots (owner-written, 3-slot rotation)
#define OFF_QACC  3168256ull   // [3][16][256] query accumulator (atomicAdd)
#define OFF_GH2A  3180544ull   // [3][16][768] gh2 accumulator (atomicAdd)
#define OFF_CLSA  3217408ull   // [3][16][16]  cls-logit accumulator
#define OFF_SMX   3218176ull   // u64[2][16][16][16]: {epoch|payload} smx records
#define OFF_FLG   3234560ull   // [16 g][16 j][16 u32] epoch flags, 64B/flag
#define WS_END    3238656ull   // 12.95 MB

__device__ __forceinline__ float b2f(u16 u){
  union { unsigned int i; float f; } x; x.i = ((unsigned int)u) << 16; return x.f;
}
__device__ __forceinline__ u16 f2b(float f){
  union { float f; unsigned int i; } x; x.f = f;
  unsigned int lsb = (x.i >> 16) & 1u;
  unsigned int r = x.i + 0x7fffu + lsb;
  return (u16)(r >> 16);
}
__device__ __forceinline__ float tanh_fast(float x){
  float e = __expf(2.f*x);
  return 1.f - 2.f/(e + 1.f);
}
__device__ __forceinline__ float sigm_fast(float x){
  return 1.f/(1.f + __expf(-x));
}
// agent-scope relaxed atomics
__device__ __forceinline__ float ldc(const float* p){
  return __hip_atomic_load((float*)p, __ATOMIC_RELAXED, __HIP_MEMORY_SCOPE_AGENT);
}
__device__ __forceinline__ void stc(float* p, float v){
  __hip_atomic_store(p, v, __ATOMIC_RELAXED, __HIP_MEMORY_SCOPE_AGENT);
}
__device__ __forceinline__ void adc(float* p, float v){
  __hip_atomic_fetch_add(p, v, __ATOMIC_RELAXED, __HIP_MEMORY_SCOPE_AGENT);
}
__device__ __forceinline__ u64 ld64(const u64* p){
  return __hip_atomic_load((u64*)p, __ATOMIC_RELAXED, __HIP_MEMORY_SCOPE_AGENT);
}
__device__ __forceinline__ void st64(u64* p, u64 v){
  __hip_atomic_store(p, v, __ATOMIC_RELAXED, __HIP_MEMORY_SCOPE_AGENT);
}
__device__ __forceinline__ unsigned fu(float f){
  union { float f; unsigned int i; } x; x.f = f; return x.i;
}
__device__ __forceinline__ float uf(unsigned u){
  union { unsigned int i; float f; } x; x.i = u; return x.f;
}

// ---------------- init: zero accumulators + smx tags + flags ----------------
__global__ void init_k(float* __restrict__ ws){
  unsigned* p = (unsigned*)(ws + OFF_QACC);
  const int n = (int)(WS_END - OFF_QACC);
  for (int i = blockIdx.x*256 + threadIdx.x; i < n; i += gridDim.x*256)
    p[i] = 0u;
}

// ---------------- state0 ----------------
__global__ void state0_k(const float* __restrict__ feats, const float* __restrict__ w_si,
                         const float* __restrict__ b_si, float* __restrict__ ws){
  const int b = blockIdx.x, tid = threadIdx.x;
  __shared__ float S[256];
  const float* row = feats + ((size_t)(b*256 + tid))*512;
  float a0=0.f,a1=0.f,a2=0.f,a3=0.f;
  for (int n=0;n<512;n+=4){ a0+=row[n]; a1+=row[n+1]; a2+=row[n+2]; a3+=row[n+3]; }
  S[tid] = (a0+a1)+(a2+a3);
  __syncthreads();
  const float* wr = w_si + (size_t)tid*256;
  float acc = 0.f;
  for (int c=0;c<256;c++) acc += wr[c]*S[c];
  ws[OFF_H0 + b*256 + tid] = acc/513.f + b_si[tid];
}

// ---------------- GI2 table ----------------
__global__ __launch_bounds__(256,2) void precomp_k(
    const float* __restrict__ feats,
    const float* __restrict__ w_ih2, const float* __restrict__ b_ih2,
    float* __restrict__ ws)
{
  const int xc = blockIdx.x;
  const int b  = blockIdx.y;
  const int tid = threadIdx.x;
  __shared__ __align__(16) float fc[256][36];
  {
    const float* fr = feats + ((size_t)(b*256 + tid))*512;
    for (int xx=0; xx<32; ++xx){
      int col = xc*32 + xx;
      fc[tid][xx] = (col >= 1 && col <= 512) ? fr[col-1] : 0.f;
    }
  }
  __syncthreads();
  const float* r0 = w_ih2 + (size_t)tid*256;
  const float* r1 = w_ih2 + (size_t)(tid+256)*256;
  const float* r2 = w_ih2 + (size_t)(tid+512)*256;
  float bb0 = b_ih2[tid], bb1 = b_ih2[tid+256], bb2 = b_ih2[tid+512];
  float acc0[32], acc1[32], acc2[32];
  #pragma unroll
  for (int xx=0; xx<32; ++xx){ acc0[xx]=bb0; acc1[xx]=bb1; acc2[xx]=bb2; }
  for (int c=0; c<256; ++c){
    float w0 = r0[c], w1 = r1[c], w2 = r2[c];
    const float* cb = &fc[c][0];
    #pragma unroll
    for (int xx=0; xx<32; ++xx){ acc0[xx]+=w0*cb[xx]; acc1[xx]+=w1*cb[xx]; acc2[xx]+=w2*cb[xx]; }
  }
  u16* tbl = (u16*)(ws + OFF_T2);
  for (int xx=0; xx<32; ++xx){
    int col = xc*32 + xx;
    if (col > 512) continue;
    size_t base = ((size_t)col*16 + b)*768;
    tbl[base + tid]       = f2b(acc0[xx]);
    tbl[base + 256 + tid] = f2b(acc1[xx]);
    tbl[base + 512 + tid] = f2b(acc2[xx]);
  }
}

// ---------------- split barrier (BAR A only) ----------------
__device__ __forceinline__ void bar_arrive(unsigned* flg, int j, unsigned ep){
  __builtin_amdgcn_s_waitcnt(0);   // drains stores AND loads of this wave
  __syncthreads();                 // all waves drained
  if (threadIdx.x == 0)
    __hip_atomic_store(flg + j*16, ep, __ATOMIC_RELAXED, __HIP_MEMORY_SCOPE_AGENT);
}
__device__ __forceinline__ void bar_wait(unsigned* flg, unsigned ep){
  if (threadIdx.x < 16){
    while (__hip_atomic_load(flg + threadIdx.x*16, __ATOMIC_RELAXED, __HIP_MEMORY_SCOPE_AGENT) < ep)
      __builtin_amdgcn_s_sleep(1);
  }
  __syncthreads();
}

// ---------------- persistent scan kernel ----------------
__global__ __launch_bounds__(256, 1) void persist_k(
    const float* __restrict__ feats,
    const float* __restrict__ w_fp,  const float* __restrict__ b_fp,
    const float* __restrict__ w_ih1, const float* __restrict__ b_ih1,
    const float* __restrict__ w_hh1, const float* __restrict__ b_hh1,
    const float* __restrict__ w_hh2, const float* __restrict__ b_hh2,
    const float* __restrict__ w_q,   const float* __restrict__ b_q,
    const float* __restrict__ w_cov, const float* __restrict__ b_cov,
    const float* __restrict__ w_cum, const float* __restrict__ b_cum,
    const float* __restrict__ w_logit, const float* __restrict__ b_logit,
    const float* __restrict__ w_c1,  const float* __restrict__ b_c1,
    const float* __restrict__ w_c2,  const float* __restrict__ b_c2,
    float* __restrict__ ws, float* __restrict__ d_out)
{
  const int tid  = threadIdx.x;
  const int g    = blockIdx.x & 15;
  const int j    = blockIdx.x >> 4;
  const int lane = tid & 63;
  const int wv   = tid >> 6;

  float* out_pred = d_out;              // [512][16]
  float* out_att  = d_out + 8192;       // [512][16][512]
  const u16* tbl2 = (const u16*)(ws + OFF_T2);

  __shared__ __align__(16) float proj_l[32*256];
  __shared__ __align__(16) float fstage[256][9];
  __shared__ float h2s[256];
  __shared__ __align__(16) float query_s[256];
  __shared__ float cbuf[2][256];
  __shared__ float cbuf2[256];
  __shared__ float ctxP[256];
  __shared__ float saw_s[40], csaw_s[40];
  __shared__ float gh1_l[48], gi1_s[48], h1n_l[16], tanh_l[16];
  __shared__ float smx_l[256];
  __shared__ float wsm[4], wss[4], wvv[4], wii[4], hi_l[3];
  __shared__ float att_l[32];
  __shared__ float payl[16];
  __shared__ float wc2s[4][16];

  // ---- register weights ----
  float wcov[4][7], wcum[4][7], wl[4];
  #pragma unroll
  for (int u=0; u<4; ++u){
    int p = 4*lane + u;
    wl[u] = w_logit[p];
    #pragma unroll
    for (int k=0; k<7; ++k){ wcov[u][k] = w_cov[p*7+k]; wcum[u][k] = w_cum[p*7+k]; }
  }
  const float blog = b_logit[0];
  const float bc20 = b_c2[0], bc21 = b_c2[1], bc22 = b_c2[2], bc23 = b_c2[3];

  const int ol = tid >> 2;
  const int qq = tid & 3;
  float bh1=0.f, bi1=0.f;
  float wh1[64], wih1[64];
  if (ol < 48){
    int gate = ol >> 4, u = ol & 15;
    int grow = gate*256 + 16*j + u;
    bh1 = b_hh1[grow]; bi1 = b_ih1[grow];
    #pragma unroll
    for (int i=0; i<64; ++i){
      wh1[i]  = w_hh1[(size_t)grow*256 + qq + 4*i];
      wih1[i] = w_ih1[(size_t)grow*256 + qq + 4*i];
    }
  } else {
    #pragma unroll
    for (int i=0; i<64; ++i){ wh1[i]=0.f; wih1[i]=0.f; }
  }
  float wqr[16];
  #pragma unroll
  for (int i=0; i<16; ++i) wqr[i] = w_q[(size_t)tid*512 + 256 + 16*j + i];
  float w2c[3][16], bg2[3];
  #pragma unroll
  for (int k=0; k<3; ++k){
    bg2[k] = b_hh2[tid + 256*k];
    #pragma unroll
    for (int i=0; i<16; ++i) w2c[k][i] = w_hh2[(size_t)(tid + 256*k)*256 + 16*j + i];
  }

  const int c_ol = tid >> 4, c_qp = tid & 15;
  const int prow = 16*j + c_ol;
  float wc1r[16], wcc[16], wcp[16], wqc[16];
  #pragma unroll
  for (int i=0; i<16; ++i){
    wc1r[i] = w_c1[(size_t)prow*768 + 512 + c_qp + 16*i];
    wcc[i]  = w_c1[(size_t)prow*768 +   0 + c_qp + 16*i];
    wcp[i]  = w_c1[(size_t)prow*768 + 256 + c_qp + 16*i];
    wqc[i]  = w_q [(size_t)prow*512 +   0 + c_qp + 16*i];
  }
  const float bcl = b_c1[prow];
  const float bqc = b_q[prow] + b_cov[prow] + b_cum[prow];

  if (tid < 64) wc2s[tid>>4][tid&15] = w_c2[(tid>>4)*256 + 16*j + (tid&15)];
  if (tid < 40){ saw_s[tid] = 0.f; csaw_s[tid] = 0.f; }

  // ---- prologue ----
  cbuf[0][tid] = feats[(size_t)(g*256 + tid)*512 + 0];
  cbuf[1][tid] = feats[(size_t)(g*256 + tid)*512 + 1];
  h2s[tid] = ws[OFF_H0 + g*256 + tid];
  {
    const float* fr = feats + ((size_t)(g*256 + tid))*512;
    const float* wr = w_fp + (size_t)tid*256;
    const float bfp = b_fp[tid];
    for (int z=0; z<4; ++z){
      for (int cc=0; cc<8; ++cc){
        int pos = 32*j + 8*z + cc;
        fstage[tid][cc] = (pos >= 1) ? fr[pos-1] : 0.f;
      }
      __syncthreads();
      float pacc[8] = {0,0,0,0,0,0,0,0};
      for (int c=0; c<256; ++c){
        float w = wr[c];
        #pragma unroll
        for (int cc=0; cc<8; ++cc) pacc[cc] += w * fstage[c][cc];
      }
      __syncthreads();
      #pragma unroll
      for (int cc=0; cc<8; ++cc) proj_l[(8*z+cc)*256 + tid] = pacc[cc] + bfp;
    }
  }
  __syncthreads();
  if (ol < 48){                // gh1(0), gi1(0)
    float s1 = 0.f, s2 = 0.f;
    #pragma unroll
    for (int i=0; i<64; ++i){
      s1 += wh1[i]*h2s[qq + 4*i];
      s2 += wih1[i]*cbuf[0][qq + 4*i];
    }
    s1 += __shfl_xor(s1, 1, 64); s1 += __shfl_xor(s1, 2, 64);
    s2 += __shfl_xor(s2, 1, 64); s2 += __shfl_xor(s2, 2, 64);
    if (qq == 0){ gh1_l[ol] = s1 + bh1; gi1_s[ol] = s2 + bi1; }
  }
  __syncthreads();
  if (tid < 16){               // h1(0) -> H1 slot 0
    int ig = 16*j + tid;
    float r  = sigm_fast(gi1_s[tid]      + gh1_l[tid]);
    float z  = sigm_fast(gi1_s[16 + tid] + gh1_l[16 + tid]);
    float nn = tanh_fast(gi1_s[32 + tid] + r*gh1_l[32 + tid]);
    float h1v = (1.f - z)*nn + z*h2s[ig];
    stc(ws + OFF_H1 + (size_t)(0*16 + g)*256 + ig, h1v);
    h1n_l[tid] = h1v;
  }
  __syncthreads();
  {                            // qh(0) -> QACC slot0
    float qs = 0.f;
    #pragma unroll
    for (int i=0; i<16; ++i) qs += wqr[i]*h1n_l[i];
    adc(ws + OFF_QACC + (size_t)(0*16 + g)*256 + tid, qs);
  }
  #pragma unroll
  for (int k=0; k<3; ++k){     // gh2(0) fold -> GH2A slot0 (+bias), bias -> slot1
    float gs = 0.f;
    #pragma unroll
    for (int i=0; i<16; ++i) gs += w2c[k][i]*h1n_l[i];
    if (j == 15) gs += bg2[k];
    adc(ws + OFF_GH2A + (size_t)(0*16 + g)*768 + 256*k + tid, gs);
    if (j == 15) adc(ws + OFF_GH2A + (size_t)(1*16 + g)*768 + 256*k + tid, bg2[k]);
  }
  {                            // qc(0)->slot0, qc(1)->slot1
    float s0v = 0.f, s1v = 0.f;
    #pragma unroll
    for (int i=0; i<16; ++i){ s0v += wqc[i]*cbuf[0][c_qp + 16*i]; s1v += wqc[i]*cbuf[1][c_qp + 16*i]; }
    s0v += __shfl_xor(s0v, 1, 64); s0v += __shfl_xor(s0v, 2, 64);
    s0v += __shfl_xor(s0v, 4, 64); s0v += __shfl_xor(s0v, 8, 64);
    s1v += __shfl_xor(s1v, 1, 64); s1v += __shfl_xor(s1v, 2, 64);
    s1v += __shfl_xor(s1v, 4, 64); s1v += __shfl_xor(s1v, 8, 64);
    if (c_qp == 0){
      adc(ws + OFF_QACC + (size_t)(0*16 + g)*256 + prow, s0v + bqc);
      adc(ws + OFF_QACC + (size_t)(1*16 + g)*256 + prow, s1v + bqc);
    }
  }
  if (j == 0 && tid < 4){      // CLSA bias seed, slots 0..2
    stc(ws + OFF_CLSA + (size_t)(0*16 + g)*16 + tid, b_c2[tid]);
    stc(ws + OFF_CLSA + (size_t)(1*16 + g)*16 + tid, b_c2[tid]);
    stc(ws + OFF_CLSA + (size_t)(2*16 + g)*16 + tid, b_c2[tid]);
  }

  unsigned* flg = (unsigned*)(ws + OFF_FLG) + g*256;
  unsigned ep = 0;
  bar_arrive(flg, j, ++ep); bar_wait(flg, ep);

  for (int t = 0; t < 512; ++t){
    const int s0 = t % 3, s1 = (t+1) % 3, s2 = (t+2) % 3;
    const unsigned need = (unsigned)(t + 1);
    u64* SMXs = (u64*)(ws + OFF_SMX) + ((size_t)((t&1)*16 + g)*256);  // [16 rec][16 u64]
    // ================= P1 =================
    {
      float qw = ldc(ws + OFF_QACC + (size_t)(s0*16 + g)*256 + tid);
      if (t < 511) cbuf[(t+1)&1][tid] = feats[(size_t)(g*256 + tid)*512 + (t+1)];
      query_s[tid] = qw;
    }
    __syncthreads();
    float lgv[8];
    {
      float qv[4];
      { float4 q4 = *(const float4*)&query_s[4*lane]; qv[0]=q4.x; qv[1]=q4.y; qv[2]=q4.z; qv[3]=q4.w; }
      #pragma unroll
      for (int i=0; i<8; ++i){
        int ln = 8*wv + i;
        float4 pj = *(const float4*)&proj_l[ln*256 + 4*lane];
        float pv[4] = {pj.x, pj.y, pj.z, pj.w};
        float sw[7], cw[7];
        #pragma unroll
        for (int k=0; k<7; ++k){ sw[k] = saw_s[ln+k]; cw[k] = csaw_s[ln+k]; }
        float sa = 0.f;
        #pragma unroll
        for (int u=0; u<4; ++u){
          float f = pv[u] + qv[u];
          #pragma unroll
          for (int k=0; k<7; ++k) f += wcov[u][k]*sw[k] + wcum[u][k]*cw[k];
          sa += wl[u]*tanh_fast(f);
        }
        #pragma unroll
        for (int mm=32; mm>=1; mm>>=1) sa += __shfl_xor(sa, mm, 64);
        lgv[i] = sa + blog;
      }
    }
    // ---- per-wave smx reduce ----
    if (lane == 0){
      float wm = -3.0e38f;
      #pragma unroll
      for (int i=0; i<8; ++i){ int n = 32*j + 8*wv + i; if (n <= t) wm = fmaxf(wm, lgv[i]); }
      wsm[wv] = wm;
      if (wv == 3){ hi_l[0] = lgv[5]; hi_l[1] = lgv[6]; hi_l[2] = lgv[7]; }
    }
    __syncthreads();
    if (lane == 0){
      float bm = fmaxf(fmaxf(wsm[0], wsm[1]), fmaxf(wsm[2], wsm[3]));
      float sm = 0.f, bv = -3.0e38f; int bi = 32*j;
      #pragma unroll
      for (int i=0; i<8; ++i){
        int n = 32*j + 8*wv + i;
        if (n <= t){ sm += __expf(lgv[i] - bm); if (lgv[i] > bv){ bv = lgv[i]; bi = n; } }
      }
      wss[wv] = sm; wvv[wv] = bv; wii[wv] = (float)bi;
    }
    __syncthreads();
    if (tid == 0){               // build record payload (10 words)
      float bm = fmaxf(fmaxf(wsm[0], wsm[1]), fmaxf(wsm[2], wsm[3]));
      float sm = wss[0] + wss[1] + wss[2] + wss[3];
      float bv = wvv[0]; float bi = wii[0];
      if (wvv[1] > bv){ bv = wvv[1]; bi = wii[1]; }
      if (wvv[2] > bv){ bv = wvv[2]; bi = wii[2]; }
      if (wvv[3] > bv){ bv = wvv[3]; bi = wii[3]; }
      payl[0] = bm; payl[1] = sm; payl[2] = bv; payl[3] = bi;
      payl[4] = lgv[0]; payl[5] = lgv[1]; payl[6] = lgv[2];
      payl[7] = hi_l[0]; payl[8] = hi_l[1]; payl[9] = hi_l[2];
    }
    // same wave (lanes 0..9 of wave0): program-order after tid0's LDS writes
    if (tid < 10)
      st64(SMXs + j*16 + tid, ((u64)need << 32) | (u64)fu(payl[tid]));
    // ---- post-record shadow ----
    float h1r = ldc(ws + OFF_H1 + (size_t)(s0*16 + g)*256 + tid);
    float ga0, ga1, ga2;
    {
      const float* gb = ws + OFF_GH2A + (size_t)(s0*16 + g)*768;
      ga0 = ldc(gb + tid); ga1 = ldc(gb + 256 + tid); ga2 = ldc(gb + 512 + tid);
    }
    if (lane == 0){
      #pragma unroll
      for (int i=0; i<8; ++i) att_l[8*wv + i] = lgv[i];
    }
    if (t < 511 && ol < 48){     // gi1(t+1): input part
      const float* cN = cbuf[(t+1)&1];
      float sgi = 0.f;
      #pragma unroll
      for (int i=0; i<64; ++i) sgi += wih1[i]*cN[qq + 4*i];
      sgi += __shfl_xor(sgi, 1, 64); sgi += __shfl_xor(sgi, 2, 64);
      if (qq == 0) gi1_s[ol] = sgi + bi1;
    }
    __syncthreads();
    if (tid < 32)
      out_att[((size_t)t*16 + g)*512 + 32*j + tid] = att_l[tid];
    if (t >= 2 && j == 0 && tid == 0){   // pred(t-2) finalize + slot reset
      float* cb = ws + OFF_CLSA + (size_t)(((t-2)%3)*16 + g)*16;
      float v0 = ldc(cb+0), v1 = ldc(cb+1), v2 = ldc(cb+2), v3 = ldc(cb+3);
      int pb = 0; float bv = v0;
      if (v1 > bv){ bv = v1; pb = 1; }
      if (v2 > bv){ bv = v2; pb = 2; }
      if (v3 > bv){ bv = v3; pb = 3; }
      out_pred[(t-2)*16 + g] = (float)pb;
      stc(cb+0, bc20); stc(cb+1, bc21); stc(cb+2, bc22); stc(cb+3, bc23);
    }
    // ================= P2 =================
    {
      const int r = tid >> 4, w = tid & 15;
      if (w < 10){
        const u64* p = SMXs + r*16 + w;
        u64 v = ld64(p);
        while ((unsigned)(v >> 32) < need){
          __builtin_amdgcn_s_sleep(1);
          v = ld64(p);
        }
        smx_l[r*16 + w] = uf((unsigned)v);
      }
    }
    if (t < 510) cbuf2[tid] = feats[(size_t)(g*256 + tid)*512 + (t+2)];
    __syncthreads();
    // combine: M, Z, argmax
    float M, invZ; int idx;
    {
      M = -3.0e38f;
      #pragma unroll
      for (int jj=0; jj<16; ++jj) M = fmaxf(M, smx_l[16*jj]);
      float Z = 0.f, bv = -3.0e38f, bif = 0.f;
      #pragma unroll
      for (int jj=0; jj<16; ++jj){
        Z += smx_l[16*jj+1]*__expf(smx_l[16*jj] - M);
        float v = smx_l[16*jj+2];
        if (v > bv){ bv = v; bif = smx_l[16*jj+3]; }
      }
      invZ = 1.f/Z; idx = (int)bif;
    }
    // issue tbl2 loads early
    const u16* t2 = tbl2 + ((size_t)idx*16 + g)*768;
    float gr = b2f(t2[tid]), gz = b2f(t2[256 + tid]), gn = b2f(t2[512 + tid]);
    // saw/csaw update (disjoint writers)
    if (lane == 0){
      #pragma unroll
      for (int i=0; i<8; ++i){
        int n = 32*j + 8*wv + i;
        float a = (n <= t) ? __expf(lgv[i] - M)*invZ : 0.f;
        saw_s[3 + 8*wv + i] = a; csaw_s[3 + 8*wv + i] += a;
      }
    } else if (tid >= 8 && tid < 11){
      int w = tid - 8; int r = 32*j - 3 + w;
      float a = 0.f;
      if (j > 0 && r <= t) a = __expf(smx_l[16*(j-1) + 7 + w] - M)*invZ;
      saw_s[w] = a; csaw_s[w] += a;
    } else if (tid >= 11 && tid < 14){
      int k = tid - 11; int r = 32*j + 32 + k;
      float a = 0.f;
      if (j < 15 && r <= t) a = __expf(smx_l[16*(j+1) + 4 + k] - M)*invZ;
      saw_s[35 + k] = a; csaw_s[35 + k] += a;
    }
    // h2(t)
    float h2v;
    {
      float r  = sigm_fast(gr + ga0);
      float z  = sigm_fast(gz + ga1);
      float nn = tanh_fast(gn + r*ga2);
      h2v = (1.f - z)*nn + z*h1r;
    }
    __syncthreads();
    h2s[tid] = h2v;
    __syncthreads();
    if (t < 511 && ol < 48){     // gh1(t+1): hidden part
      float sg = 0.f;
      #pragma unroll
      for (int i=0; i<64; ++i) sg += wh1[i]*h2s[qq + 4*i];
      sg += __shfl_xor(sg, 1, 64); sg += __shfl_xor(sg, 2, 64);
      if (qq == 0) gh1_l[ol] = sg + bh1;
    }
    __syncthreads();
    if (t < 511 && tid < 16){    // h1(t+1) own rows -> H1 slot s1
      int ig = 16*j + tid;
      float r  = sigm_fast(gi1_s[tid]      + gh1_l[tid]);
      float z  = sigm_fast(gi1_s[16 + tid] + gh1_l[16 + tid]);
      float nn = tanh_fast(gi1_s[32 + tid] + r*gh1_l[32 + tid]);
      float h1v = (1.f - z)*nn + z*h2s[ig];
      stc(ws + OFF_H1 + (size_t)(s1*16 + g)*256 + ig, h1v);
      h1n_l[tid] = h1v;
    }
    __syncthreads();
    if (t < 511){                // folds into slot s1
      float qs = 0.f;
      #pragma unroll
      for (int i=0; i<16; ++i) qs += wqr[i]*h1n_l[i];
      adc(ws + OFF_QACC + (size_t)(s1*16 + g)*256 + tid, qs);
      #pragma unroll
      for (int k=0; k<3; ++k){
        float gs = 0.f;
        #pragma unroll
        for (int i=0; i<16; ++i) gs += w2c[k][i]*h1n_l[i];
        adc(ws + OFF_GH2A + (size_t)(s1*16 + g)*768 + 256*k + tid, gs);
      }
    }
    if (t < 510){                // resets of slot s2 (pre-arrive: drained by arrive)
      float qn = 0.f;
      #pragma unroll
      for (int i=0; i<16; ++i) qn += wqc[i]*cbuf2[c_qp + 16*i];
      qn += __shfl_xor(qn, 1, 64); qn += __shfl_xor(qn, 2, 64);
      qn += __shfl_xor(qn, 4, 64); qn += __shfl_xor(qn, 8, 64);
      if (c_qp == 0) stc(ws + OFF_QACC + (size_t)(s2*16 + g)*256 + prow, qn + bqc);
      if (j == 15){
        float* gb = ws + OFF_GH2A + (size_t)(s2*16 + g)*768;
        stc(gb + tid, bg2[0]); stc(gb + 256 + tid, bg2[1]); stc(gb + 512 + tid, bg2[2]);
      }
    }
    bar_arrive(flg, j, ++ep);    // BAR A arrive
    // -------- shadow: off-recurrence work --------
    ctxP[tid] = (idx >= 1) ? feats[(size_t)(g*256 + tid)*512 + idx - 1] : 0.f;
    __syncthreads();
    {
      const float* cT = cbuf[t&1];
      float sc = 0.f;
      #pragma unroll
      for (int i=0; i<16; ++i){
        int d = c_qp + 16*i;
        sc += wc1r[i]*h2s[d] + wcc[i]*cT[d] + wcp[i]*ctxP[d];
      }
      sc += __shfl_xor(sc, 1, 64); sc += __shfl_xor(sc, 2, 64);
      sc += __shfl_xor(sc, 4, 64); sc += __shfl_xor(sc, 8, 64);
      if (c_qp == 0) tanh_l[c_ol] = tanh_fast(sc + bcl);
    }
    __syncthreads();
    if (tid < 4){                // CLSA adds into slot s0
      float sum = 0.f;
      #pragma unroll
      for (int o=0; o<16; ++o) sum += wc2s[tid][o]*tanh_l[o];
      adc(ws + OFF_CLSA + (size_t)(s0*16 + g)*16 + tid, sum);
    }
    bar_wait(flg, ep);           // BAR A wait
  }
  // tail: pred(510), pred(511)
  bar_arrive(flg, j, ++ep); bar_wait(flg, ep);
  if (j == 0 && tid == 0){
    #pragma unroll
    for (int tt=510; tt<512; ++tt){
      float* cb = ws + OFF_CLSA + (size_t)((tt%3)*16 + g)*16;
      float v0 = ldc(cb+0), v1 = ldc(cb+1), v2 = ldc(cb+2), v3 = ldc(cb+3);
      int pb = 0; float bv = v0;
      if (v1 > bv){ bv = v1; pb = 1; }
      if (v2 > bv){ bv = v2; pb = 2; }
      if (v3 > bv){ bv = v3; pb = 3; }
      out_pred[tt*16 + g] = (float)pb;
    }
  }
}

extern "C" void kernel_launch(void* const* d_in, const int* in_sizes, int n_in,
                              void* d_out, int out_size, void* d_ws, size_t ws_size,
                              hipStream_t stream)
{
  (void)in_sizes; (void)n_in; (void)out_size; (void)ws_size;
  const float* feats   = (const float*)d_in[0];
  const float* w_fp    = (const float*)d_in[2];
  const float* b_fp    = (const float*)d_in[3];
  const float* w_si    = (const float*)d_in[4];
  const float* b_si    = (const float*)d_in[5];
  const float* w_ih1   = (const float*)d_in[6];
  const float* w_hh1   = (const float*)d_in[7];
  const float* b_ih1   = (const float*)d_in[8];
  const float* b_hh1   = (const float*)d_in[9];
  const float* w_ih2   = (const float*)d_in[10];
  const float* w_hh2   = (const float*)d_in[11];
  const float* b_ih2   = (const float*)d_in[12];
  const float* b_hh2   = (const float*)d_in[13];
  const float* w_q     = (const float*)d_in[14];
  const float* b_q     = (const float*)d_in[15];
  const float* w_cov   = (const float*)d_in[16];
  const float* b_cov   = (const float*)d_in[17];
  const float* w_cum   = (const float*)d_in[18];
  const float* b_cum   = (const float*)d_in[19];
  const float* w_logit = (const float*)d_in[20];
  const float* b_logit = (const float*)d_in[21];
  const float* w_c1    = (const float*)d_in[22];
  const float* b_c1    = (const float*)d_in[23];
  const float* w_c2    = (const float*)d_in[24];
  const float* b_c2    = (const float*)d_in[25];
  float* ws  = (float*)d_ws;
  float* out = (float*)d_out;

  init_k<<<64, 256, 0, stream>>>(ws);
  state0_k<<<16, 256, 0, stream>>>(feats, w_si, b_si, ws);
  precomp_k<<<dim3(17,16), 256, 0, stream>>>(feats, w_ih2, b_ih2, ws);
  persist_k<<<256, 256, 0, stream>>>(feats, w_fp, b_fp, w_ih1, b_ih1,
                                     w_hh1, b_hh1, w_hh2, b_hh2,
                                     w_q, b_q, w_cov, b_cov, w_cum, b_cum,
                                     w_logit, b_logit, w_c1, b_c1, w_c2, b_c2,
                                     ws, out);
}